// Round 9
// baseline (1853.184 us; speedup 1.0000x reference)
//
#include <hip/hip_runtime.h>

// CRF Viterbi decode: B=64, T=1024, K=256.
// emissions [B,T,K] f32, transitions [K,K] f32 (prev->next). out [B,T] f32 tags.
//
// Pipeline (M 64MB + gid 16.75MB + Tt 256KB + maps 256KB + exits 4KB ~= 81.3MB):
//   1. crf_transpose_trans: Tt[k][p] = trans[p][k] (proven).
//   2. crf_forward_states : packed-f32 (v_pk_add/max) inner loop; stores
//      pre-emission max M[t][k] AND winning-group id gid[t][k] (3 bits, u8).
//      Group id = first group attaining the max (strict-> ascending scan).
//   3. crf_seg_maps_fused : per (b,seg): recompute bp rows in LDS using gid
//      (scan only the winning 32-prev group; first-index ties = jnp.argmax),
//      then chase all 256 candidates -> segment entry map.
//   4. crf_compose        : final-state argmax (M+em) + 16 map hops (proven).
//   5. crf_emit_fused     : recompute bp rows, chase winner, write tags.

#define CRF_B 64
#define CRF_T 1024
#define CRF_K 256
#define NSEG  16
#define SEGLEN 64

#define FG 8
#define FP 32

typedef float v2f __attribute__((ext_vector_type(2)));
__device__ __forceinline__ v2f pk_max(v2f a, v2f b) {
    return __builtin_elementwise_max(a, b);
}

// ---------------------------------------------------------------------------
// Transpose (proven round 2)
// ---------------------------------------------------------------------------

__global__ void crf_transpose_trans(const float* __restrict__ trans,
                                    float* __restrict__ Tt)
{
    const int k = blockIdx.x;
    const int p = threadIdx.x;
    Tt[(size_t)k * CRF_K + p] = trans[(size_t)p * CRF_K + k];
}

// ---------------------------------------------------------------------------
// Forward: proven structure; inner loop on packed f32 pairs; stores M + gid.
// ---------------------------------------------------------------------------

#define LD4(v, p, col) { \
    v.x = trans[(size_t)(p) * CRF_K + (col)]; \
    v.y = trans[(size_t)((p) + 1) * CRF_K + (col)]; \
    v.z = trans[(size_t)((p) + 2) * CRF_K + (col)]; \
    v.w = trans[(size_t)((p) + 3) * CRF_K + (col)]; }

#define FWD_CHUNK(idx, ta, tb) { \
    float4 sv = sp[idx]; \
    v2f sA; sA.x = sv.x; sA.y = sv.y; \
    v2f sB; sB.x = sv.z; sB.y = sv.w; \
    v2f tA0; tA0.x = ta.x; tA0.y = ta.y; \
    v2f tA1; tA1.x = ta.z; tA1.y = ta.w; \
    v2f tB0; tB0.x = tb.x; tB0.y = tb.y; \
    v2f tB1; tB1.x = tb.z; tB1.y = tb.w; \
    macc0 = pk_max(macc0, pk_max(sA + tA0, sB + tA1)); \
    macc1 = pk_max(macc1, pk_max(sA + tB0, sB + tB1)); }

__global__ __launch_bounds__(1024, 4) void crf_forward_states(
    const float* __restrict__ em, const float* __restrict__ trans,
    float* __restrict__ M, unsigned char* __restrict__ gid)
{
    const int b   = blockIdx.x;
    const int tid = threadIdx.x;
    const int g   = tid >> 7;      // prev group 0..7
    const int c   = tid & 127;     // columns c and c+128

    __shared__ __align__(16) float s_state[CRF_K];
    __shared__ float s_partial[FG][CRF_K];

    const int pbase = g * FP;
    const int c2    = c + 128;

    float4 ta0, ta1, ta2, ta3, ta4, ta5, ta6, ta7;
    float4 tb0, tb1, tb2, tb3, tb4, tb5, tb6, tb7;
    LD4(ta0, pbase +  0, c)  LD4(ta1, pbase +  4, c)
    LD4(ta2, pbase +  8, c)  LD4(ta3, pbase + 12, c)
    LD4(ta4, pbase + 16, c)  LD4(ta5, pbase + 20, c)
    LD4(ta6, pbase + 24, c)  LD4(ta7, pbase + 28, c)
    LD4(tb0, pbase +  0, c2) LD4(tb1, pbase +  4, c2)
    LD4(tb2, pbase +  8, c2) LD4(tb3, pbase + 12, c2)
    LD4(tb4, pbase + 16, c2) LD4(tb5, pbase + 20, c2)
    LD4(tb6, pbase + 24, c2) LD4(tb7, pbase + 28, c2)

    const float* emb = em + (size_t)b * CRF_T * CRF_K;
    if (tid < CRF_K) s_state[tid] = emb[tid];          // state[0] = em[0]
    float e_cur = 0.0f;
    if (tid < CRF_K) e_cur = emb[CRF_K + tid];         // emission for t = 1
    __syncthreads();

    for (int t = 1; t < CRF_T; ++t) {
        float e_next = 0.0f;
        if (tid < CRF_K && t + 1 < CRF_T)
            e_next = emb[(t + 1) * CRF_K + tid];

        v2f macc0; macc0.x = -INFINITY; macc0.y = -INFINITY;
        v2f macc1; macc1.x = -INFINITY; macc1.y = -INFINITY;
        const float4* sp = (const float4*)(s_state + pbase);
        FWD_CHUNK(0, ta0, tb0) FWD_CHUNK(1, ta1, tb1)
        FWD_CHUNK(2, ta2, tb2) FWD_CHUNK(3, ta3, tb3)
        FWD_CHUNK(4, ta4, tb4) FWD_CHUNK(5, ta5, tb5)
        FWD_CHUNK(6, ta6, tb6) FWD_CHUNK(7, ta7, tb7)

        s_partial[g][c]  = fmaxf(macc0.x, macc0.y);
        s_partial[g][c2] = fmaxf(macc1.x, macc1.y);
        __syncthreads();
        if (tid < CRF_K) {
            float bv = s_partial[0][tid];
            int   bg = 0;
#pragma unroll
            for (int j = 1; j < FG; ++j) {
                float pv = s_partial[j][tid];
                if (pv > bv) { bv = pv; bg = j; }   // first group w/ max
            }
            s_state[tid] = bv + e_cur;
            M[((size_t)t * CRF_B + b) * CRF_K + tid]   = bv;   // PRE-emission
            gid[((size_t)t * CRF_B + b) * CRF_K + tid] = (unsigned char)bg;
        }
        __syncthreads();
        e_cur = e_next;
    }
}

// ---------------------------------------------------------------------------
// bp-row recompute core: entry (t1, k) scans ONLY the winning group's 32
// prevs (group from gid[t1+1][k]). state = M[t1]+em[t1] (em only at t1=0) —
// bit-exact vs forward; strict-> ascending scan = first-index = jnp.argmax.
// ---------------------------------------------------------------------------

#define SCAN4(sm, tv, pidx) { \
    float v0 = sm.x + tv.x; if (v0 > best) { best = v0; arg = (pidx); } \
    float v1 = sm.y + tv.y; if (v1 > best) { best = v1; arg = (pidx) + 1; } \
    float v2 = sm.z + tv.z; if (v2 > best) { best = v2; arg = (pidx) + 2; } \
    float v3 = sm.w + tv.w; if (v3 > best) { best = v3; arg = (pidx) + 3; } }

__device__ __forceinline__ int bp_entry(
    int t1, int b, int k,
    const float* __restrict__ M, const float* __restrict__ em,
    const float* __restrict__ Tt, const unsigned char* __restrict__ gid)
{
    const int g    = gid[((size_t)(t1 + 1) * CRF_B + b) * CRF_K + k];
    const int base = g * FP;

    const float4* T4 = (const float4*)(Tt + (size_t)k * CRF_K + base);
    const float4* E4 = (const float4*)(em + ((size_t)b * CRF_T + t1) * CRF_K + base);

    float best = -INFINITY;
    int   arg  = base;
    if (t1 == 0) {
#pragma unroll
        for (int i = 0; i < 8; ++i) {
            float4 sm = E4[i];
            float4 tv = T4[i];
            SCAN4(sm, tv, base + 4 * i)
        }
    } else {
        const float4* M4 = (const float4*)(M + ((size_t)t1 * CRF_B + b) * CRF_K + base);
#pragma unroll
        for (int i = 0; i < 8; ++i) {
            float4 mm = M4[i];
            float4 ee = E4[i];
            float4 sm;
            sm.x = mm.x + ee.x; sm.y = mm.y + ee.y;
            sm.z = mm.z + ee.z; sm.w = mm.w + ee.w;
            float4 tv = T4[i];
            SCAN4(sm, tv, base + 4 * i)
        }
    }
    return arg;
}

// ---------------------------------------------------------------------------
// Segment maps (fused bp recompute): 1024 blocks x 256 thr.
// ---------------------------------------------------------------------------

__global__ __launch_bounds__(256) void crf_seg_maps_fused(
    const float* __restrict__ M, const float* __restrict__ em,
    const float* __restrict__ Tt, const unsigned char* __restrict__ gid,
    unsigned char* __restrict__ maps)
{
    const int b   = blockIdx.x >> 4;
    const int s   = blockIdx.x & 15;
    const int tid = threadIdx.x;
    const int rows = (s == NSEG - 1) ? SEGLEN - 1 : SEGLEN;
    const int r0   = s * SEGLEN;

    __shared__ unsigned char lbp[SEGLEN][CRF_K];   // 16 KB

    for (int j = 0; j < rows; ++j)
        lbp[j][tid] = (unsigned char)bp_entry(r0 + j, b, tid, M, em, Tt, gid);
    __syncthreads();

    int tag = tid;
    for (int j = rows - 1; j >= 0; --j) tag = lbp[j][tag];
    maps[((size_t)b * NSEG + s) * CRF_K + tid] = (unsigned char)tag;
}

// ---------------------------------------------------------------------------
// Compose (proven round 8): last-tag argmax over M+em + 16 map hops.
// ---------------------------------------------------------------------------

__global__ __launch_bounds__(256) void crf_compose(
    const float* __restrict__ M, const float* __restrict__ em,
    const unsigned char* __restrict__ maps,
    int* __restrict__ exits, float* __restrict__ out)
{
    const int b   = blockIdx.x;
    const int tid = threadIdx.x;

    __shared__ float s_wv[4];
    __shared__ int   s_wi[4];

    float v = M[((size_t)(CRF_T - 1) * CRF_B + b) * CRF_K + tid]
            + em[((size_t)b * CRF_T + (CRF_T - 1)) * CRF_K + tid];
    int   i = tid;
#pragma unroll
    for (int off = 32; off >= 1; off >>= 1) {
        float ov = __shfl_xor(v, off, 64);
        int   oi = __shfl_xor(i, off, 64);
        if (ov > v || (ov == v && oi < i)) { v = ov; i = oi; }
    }
    const int lane = tid & 63, wv = tid >> 6;
    if (lane == 0) { s_wv[wv] = v; s_wi[wv] = i; }
    __syncthreads();
    if (tid == 0) {
        float bv = s_wv[0]; int bi = s_wi[0];
#pragma unroll
        for (int w = 1; w < 4; ++w)
            if (s_wv[w] > bv) { bv = s_wv[w]; bi = s_wi[w]; }
        out[(size_t)b * CRF_T + (CRF_T - 1)] = (float)bi;
        int E = bi;
        exits[b * NSEG + NSEG - 1] = E;
        const unsigned char* mb = maps + (size_t)b * NSEG * CRF_K;
        for (int s = NSEG - 1; s >= 1; --s) {
            E = mb[(size_t)s * CRF_K + E];
            exits[b * NSEG + s - 1] = E;
        }
    }
}

// ---------------------------------------------------------------------------
// Emit (fused bp recompute): 1024 blocks x 256 thr; winner writes tags.
// ---------------------------------------------------------------------------

__global__ __launch_bounds__(256) void crf_emit_fused(
    const float* __restrict__ M, const float* __restrict__ em,
    const float* __restrict__ Tt, const unsigned char* __restrict__ gid,
    const int* __restrict__ exits, float* __restrict__ out)
{
    const int b   = blockIdx.x >> 4;
    const int s   = blockIdx.x & 15;
    const int tid = threadIdx.x;
    const int rows = (s == NSEG - 1) ? SEGLEN - 1 : SEGLEN;
    const int r0   = s * SEGLEN;

    __shared__ unsigned char lbp[SEGLEN][CRF_K];

    for (int j = 0; j < rows; ++j)
        lbp[j][tid] = (unsigned char)bp_entry(r0 + j, b, tid, M, em, Tt, gid);
    __syncthreads();

    int tag = tid;
    const bool win = (tid == exits[b * NSEG + s]);
    for (int j = rows - 1; j >= 0; --j) {
        tag = lbp[j][tag];
        if (win) out[(size_t)b * CRF_T + r0 + j] = (float)tag;
    }
}

__global__ void crf_zero_out(float* __restrict__ out, int n)
{
    int i = blockIdx.x * blockDim.x + threadIdx.x;
    if (i < n) out[i] = 0.0f;
}

// ---------------------------------------------------------------------------

extern "C" void kernel_launch(void* const* d_in, const int* in_sizes, int n_in,
                              void* d_out, int out_size, void* d_ws, size_t ws_size,
                              hipStream_t stream) {
    (void)in_sizes; (void)n_in;
    const float* em    = (const float*)d_in[0];   // [B,T,K]
    const float* trans = (const float*)d_in[1];   // [K,K]
    float* out = (float*)d_out;                   // [B,T]

    const size_t M_bytes     = (size_t)CRF_T * CRF_B * CRF_K * sizeof(float); // 64 MB
    const size_t gid_bytes   = (size_t)CRF_T * CRF_B * CRF_K;                 // 16.75 MB
    const size_t tt_bytes    = (size_t)CRF_K * CRF_K * sizeof(float);         // 256 KB
    const size_t maps_bytes  = (size_t)CRF_B * NSEG * CRF_K;                  // 256 KB
    const size_t exits_bytes = (size_t)CRF_B * NSEG * sizeof(int);            // 4 KB

    char* w = (char*)d_ws;
    if (ws_size >= M_bytes + gid_bytes + tt_bytes + maps_bytes + exits_bytes) {
        float*         M     = (float*)w;            w += M_bytes;
        unsigned char* gid   = (unsigned char*)w;    w += gid_bytes;
        float*         Tt    = (float*)w;            w += tt_bytes;
        unsigned char* maps  = (unsigned char*)w;    w += maps_bytes;
        int*           exits = (int*)w;

        crf_transpose_trans<<<CRF_K, CRF_K, 0, stream>>>(trans, Tt);
        crf_forward_states<<<CRF_B, 1024, 0, stream>>>(em, trans, M, gid);
        crf_seg_maps_fused<<<CRF_B * NSEG, 256, 0, stream>>>(M, em, Tt, gid, maps);
        crf_compose<<<CRF_B, 256, 0, stream>>>(M, em, maps, exits, out);
        crf_emit_fused<<<CRF_B * NSEG, 256, 0, stream>>>(M, em, Tt, gid, exits, out);
    } else {
        crf_zero_out<<<(out_size + 255) / 256, 256, 0, stream>>>(out, out_size);
    }
}

// Round 10
// 1317.290 us; speedup vs baseline: 1.4068x; 1.4068x over previous
//
#include <hip/hip_runtime.h>

// CRF Viterbi decode: B=64, T=1024, K=256.
// emissions [B,T,K] f32, transitions [K,K] f32 (prev->next). out [B,T] f32 tags.
//
// Path A (M 64MB + gidp 8.4MB + bp 16.75MB + maps 256KB + exits 4KB ~ 88.2MB):
//   1. crf_forward_states : proven r6 body; stores pre-emission max M[t][k] and
//      winning-group nibble gidp (first of 8 32-prev groups attaining the max).
//   2. crf_bp_gid         : backpointers scanning ONLY the winning 32-prev group
//      (bit-exact: global first-index argmax lies in the first max-attaining
//      group; within-group ascending strict-> = first-index). Trans staged
//      transposed in a 64KB LDS tile; conflict-free b32 reads.
//   3. crf_seg_maps / crf_compose / crf_emit : proven segmented chase.
// Path B (~80.2MB, proven r5 shape): forward(no gid) + bp_matrix(full scan on
// M+em) + chase.  Path C: zero out.

#define CRF_B 64
#define CRF_T 1024
#define CRF_K 256
#define NSEG  16
#define SEGLEN 64

#define FG 8
#define FP 32

// ---------------------------------------------------------------------------
// Forward: proven round-6 named-reg body. Reducer: compare-scan (first group
// attaining max) + nibble-packed gid store (2 cols/byte). gidp may be null.
// ---------------------------------------------------------------------------

#define LD4(v, p, col) { \
    v.x = trans[(size_t)(p) * CRF_K + (col)]; \
    v.y = trans[(size_t)((p) + 1) * CRF_K + (col)]; \
    v.z = trans[(size_t)((p) + 2) * CRF_K + (col)]; \
    v.w = trans[(size_t)((p) + 3) * CRF_K + (col)]; }

#define FWD_CHUNK(idx, ta, tb) { \
    float4 sv = sp[idx]; \
    float a0 = sv.x + ta.x; \
    float a1 = sv.y + ta.y; \
    float a2 = sv.z + ta.z; \
    float a3 = sv.w + ta.w; \
    m0 = fmaxf(m0, fmaxf(fmaxf(a0, a1), fmaxf(a2, a3))); \
    float c0 = sv.x + tb.x; \
    float c1 = sv.y + tb.y; \
    float c2 = sv.z + tb.z; \
    float c3 = sv.w + tb.w; \
    m1 = fmaxf(m1, fmaxf(fmaxf(c0, c1), fmaxf(c2, c3))); }

__global__ __launch_bounds__(1024, 4) void crf_forward_states(
    const float* __restrict__ em, const float* __restrict__ trans,
    float* __restrict__ M, unsigned char* __restrict__ gidp)
{
    const int b   = blockIdx.x;
    const int tid = threadIdx.x;
    const int g   = tid >> 7;      // prev group 0..7
    const int c   = tid & 127;     // columns c and c+128

    __shared__ __align__(16) float s_state[CRF_K];
    __shared__ float s_partial[FG][CRF_K];

    const int pbase = g * FP;
    const int c2    = c + 128;

    float4 ta0, ta1, ta2, ta3, ta4, ta5, ta6, ta7;
    float4 tb0, tb1, tb2, tb3, tb4, tb5, tb6, tb7;
    LD4(ta0, pbase +  0, c)  LD4(ta1, pbase +  4, c)
    LD4(ta2, pbase +  8, c)  LD4(ta3, pbase + 12, c)
    LD4(ta4, pbase + 16, c)  LD4(ta5, pbase + 20, c)
    LD4(ta6, pbase + 24, c)  LD4(ta7, pbase + 28, c)
    LD4(tb0, pbase +  0, c2) LD4(tb1, pbase +  4, c2)
    LD4(tb2, pbase +  8, c2) LD4(tb3, pbase + 12, c2)
    LD4(tb4, pbase + 16, c2) LD4(tb5, pbase + 20, c2)
    LD4(tb6, pbase + 24, c2) LD4(tb7, pbase + 28, c2)

    const float* emb = em + (size_t)b * CRF_T * CRF_K;
    if (tid < CRF_K) s_state[tid] = emb[tid];          // state[0] = em[0]
    float e_cur = 0.0f;
    if (tid < CRF_K) e_cur = emb[CRF_K + tid];         // emission for t = 1
    __syncthreads();

    for (int t = 1; t < CRF_T; ++t) {
        float e_next = 0.0f;
        if (tid < CRF_K && t + 1 < CRF_T)
            e_next = emb[(t + 1) * CRF_K + tid];

        float m0 = -INFINITY, m1 = -INFINITY;
        const float4* sp = (const float4*)(s_state + pbase);
        FWD_CHUNK(0, ta0, tb0) FWD_CHUNK(1, ta1, tb1)
        FWD_CHUNK(2, ta2, tb2) FWD_CHUNK(3, ta3, tb3)
        FWD_CHUNK(4, ta4, tb4) FWD_CHUNK(5, ta5, tb5)
        FWD_CHUNK(6, ta6, tb6) FWD_CHUNK(7, ta7, tb7)

        s_partial[g][c]  = m0;
        s_partial[g][c2] = m1;
        __syncthreads();
        if (tid < CRF_K) {
            float bv = s_partial[0][tid];
            int   bg = 0;
#pragma unroll
            for (int j = 1; j < FG; ++j) {
                float pv = s_partial[j][tid];
                if (pv > bv) { bv = pv; bg = j; }   // first group with max
            }
            s_state[tid] = bv + e_cur;
            M[((size_t)t * CRF_B + b) * CRF_K + tid] = bv;   // PRE-emission
            if (gidp) {
                int g1 = __shfl_down(bg, 1, 64);   // cols pair within wave
                if ((tid & 1) == 0)
                    gidp[((size_t)t * CRF_B + b) * 128 + (tid >> 1)] =
                        (unsigned char)(bg | (g1 << 4));
            }
        }
        __syncthreads();
        e_cur = e_next;
    }
}

// ---------------------------------------------------------------------------
// bp via gid: 512 blocks (b x colgroup64 x tsplit2) x 128 thr (2 waves).
// LDS: trans transposed tile s_tile[prev][col] (64KB, staged once; reads
// s_tile[base+i][lane] hit bank lane&31 -> 2-way = free). Per t1: gid nibble,
// state row = M+em float4 loads, 32-prev ascending strict-> scan.
// ---------------------------------------------------------------------------

#define BPG_CHUNK(j) { \
    float4 mm = M4[j]; float4 ee = E4[j]; \
    float s0 = mm.x + ee.x, s1 = mm.y + ee.y; \
    float s2 = mm.z + ee.z, s3 = mm.w + ee.w; \
    float t0v = s_tile[base + 4*(j) + 0][lane]; \
    float t1v = s_tile[base + 4*(j) + 1][lane]; \
    float t2v = s_tile[base + 4*(j) + 2][lane]; \
    float t3v = s_tile[base + 4*(j) + 3][lane]; \
    float v0 = s0 + t0v; if (v0 > best) { best = v0; arg = base + 4*(j); } \
    float v1 = s1 + t1v; if (v1 > best) { best = v1; arg = base + 4*(j) + 1; } \
    float v2 = s2 + t2v; if (v2 > best) { best = v2; arg = base + 4*(j) + 2; } \
    float v3 = s3 + t3v; if (v3 > best) { best = v3; arg = base + 4*(j) + 3; } }

#define BPG_CHUNK0(j) { \
    float4 ee = E4[j]; \
    float t0v = s_tile[base + 4*(j) + 0][lane]; \
    float t1v = s_tile[base + 4*(j) + 1][lane]; \
    float t2v = s_tile[base + 4*(j) + 2][lane]; \
    float t3v = s_tile[base + 4*(j) + 3][lane]; \
    float v0 = ee.x + t0v; if (v0 > best) { best = v0; arg = base + 4*(j); } \
    float v1 = ee.y + t1v; if (v1 > best) { best = v1; arg = base + 4*(j) + 1; } \
    float v2 = ee.z + t2v; if (v2 > best) { best = v2; arg = base + 4*(j) + 2; } \
    float v3 = ee.w + t3v; if (v3 > best) { best = v3; arg = base + 4*(j) + 3; } }

__global__ __launch_bounds__(128) void crf_bp_gid(
    const float* __restrict__ M, const float* __restrict__ em,
    const float* __restrict__ trans, const unsigned char* __restrict__ gidp,
    unsigned char* __restrict__ bp)
{
    const int b    = blockIdx.x >> 3;
    const int cg   = (blockIdx.x >> 1) & 3;
    const int ts   = blockIdx.x & 1;
    const int tid  = threadIdx.x;
    const int lane = tid & 63;
    const int w    = tid >> 6;      // wave 0/1

    __shared__ float s_tile[CRF_K][64];   // 64 KB: s_tile[prev][col]

    const int k0 = cg * 64;
    for (int idx = tid; idx < CRF_K * 64; idx += 128) {
        const int p = idx >> 6, cc = idx & 63;
        s_tile[p][cc] = trans[(size_t)p * CRF_K + k0 + cc];
    }
    __syncthreads();

    const int t_lo = ts * 512;
    const int t_hi = ts ? (CRF_T - 1) : 512;
    const int half = (k0 >> 1) + (lane >> 1);

    int t1 = t_lo + w;

    if (t1 == 0) {   // state[0] = em[0] (M row 0 is unwritten)
        const unsigned char gb = gidp[((size_t)1 * CRF_B + b) * 128 + half];
        const int g    = (lane & 1) ? ((gb >> 4) & 7) : (gb & 7);
        const int base = g << 5;
        const float4* E4 =
            (const float4*)(em + (size_t)b * CRF_T * CRF_K + base);
        float best = -INFINITY; int arg = base;
        BPG_CHUNK0(0) BPG_CHUNK0(1) BPG_CHUNK0(2) BPG_CHUNK0(3)
        BPG_CHUNK0(4) BPG_CHUNK0(5) BPG_CHUNK0(6) BPG_CHUNK0(7)
        bp[((size_t)b * (CRF_T - 1) + 0) * CRF_K + k0 + lane] =
            (unsigned char)arg;
        t1 += 2;
    }

    for (; t1 < t_hi; t1 += 2) {
        const unsigned char gb =
            gidp[((size_t)(t1 + 1) * CRF_B + b) * 128 + half];
        const int g    = (lane & 1) ? ((gb >> 4) & 7) : (gb & 7);
        const int base = g << 5;
        const float4* M4 =
            (const float4*)(M + ((size_t)t1 * CRF_B + b) * CRF_K + base);
        const float4* E4 =
            (const float4*)(em + ((size_t)b * CRF_T + t1) * CRF_K + base);
        float best = -INFINITY; int arg = base;
        BPG_CHUNK(0) BPG_CHUNK(1) BPG_CHUNK(2) BPG_CHUNK(3)
        BPG_CHUNK(4) BPG_CHUNK(5) BPG_CHUNK(6) BPG_CHUNK(7)
        bp[((size_t)b * (CRF_T - 1) + t1) * CRF_K + k0 + lane] =
            (unsigned char)arg;
    }
}

// ---------------------------------------------------------------------------
// Fallback-B backpointers: round-5 proven bp_matrix, state staged as M+em.
// ---------------------------------------------------------------------------

__global__ __launch_bounds__(1024, 2) void crf_bp_matrix(
    const float* __restrict__ M, const float* __restrict__ em,
    const float* __restrict__ trans, unsigned char* __restrict__ bp)
{
    const int b   = blockIdx.x >> 4;
    const int seg = blockIdx.x & 15;
    const int tid = threadIdx.x;
    const int g   = tid >> 8;      // 0..3
    const int k   = tid & 255;

    __shared__ __align__(16) float s_row[CRF_K];
    __shared__ float s_pv[4][CRF_K];
    __shared__ int   s_pi[4][CRF_K];

    const int pbase = g * 64;
    float4 tr[16];
#pragma unroll
    for (int i = 0; i < 16; ++i) {
        const int p = pbase + 4 * i;
        tr[i].x = trans[(p + 0) * CRF_K + k];
        tr[i].y = trans[(p + 1) * CRF_K + k];
        tr[i].z = trans[(p + 2) * CRF_K + k];
        tr[i].w = trans[(p + 3) * CRF_K + k];
    }

    const int t_lo = seg * SEGLEN;
    const int t_hi = min(t_lo + SEGLEN, CRF_T - 1);
    unsigned char* bpb = bp + (size_t)b * (CRF_T - 1) * CRF_K;

    for (int t1 = t_lo; t1 < t_hi; ++t1) {
        if (tid < CRF_K) {
            float ev = em[((size_t)b * CRF_T + t1) * CRF_K + tid];
            float sv = ev;
            if (t1 > 0) sv = M[((size_t)t1 * CRF_B + b) * CRF_K + tid] + ev;
            s_row[tid] = sv;
        }
        __syncthreads();

        float best = -INFINITY;
        int   arg  = pbase;
        const float4* sp = (const float4*)(s_row + pbase);
#pragma unroll
        for (int i = 0; i < 16; ++i) {
            float4 st = sp[i];
            const int p = pbase + 4 * i;
            float s0 = st.x + tr[i].x;
            float s1 = st.y + tr[i].y;
            float s2 = st.z + tr[i].z;
            float s3 = st.w + tr[i].w;
            if (s0 > best) { best = s0; arg = p; }
            if (s1 > best) { best = s1; arg = p + 1; }
            if (s2 > best) { best = s2; arg = p + 2; }
            if (s3 > best) { best = s3; arg = p + 3; }
        }
        s_pv[g][k] = best;
        s_pi[g][k] = arg;
        __syncthreads();
        if (tid < CRF_K) {
            float bv = s_pv[0][tid];
            int   ba = s_pi[0][tid];
#pragma unroll
            for (int j = 1; j < 4; ++j) {
                float v = s_pv[j][tid];
                if (v > bv) { bv = v; ba = s_pi[j][tid]; }
            }
            bpb[(size_t)t1 * CRF_K + tid] = (unsigned char)ba;
        }
        __syncthreads();
    }
}

// ---------------------------------------------------------------------------
// Segmented chase (proven): seg_maps -> compose -> emit.
// ---------------------------------------------------------------------------

__global__ __launch_bounds__(256) void crf_seg_maps(
    const unsigned char* __restrict__ bp, unsigned char* __restrict__ maps)
{
    const int b   = blockIdx.x >> 4;
    const int s   = blockIdx.x & 15;
    const int tid = threadIdx.x;
    const int rows = (s == NSEG - 1) ? SEGLEN - 1 : SEGLEN;
    const int r0   = s * SEGLEN;

    __shared__ unsigned char lbp[SEGLEN][CRF_K];   // 16 KB

    const unsigned char* bpb = bp + (size_t)b * (CRF_T - 1) * CRF_K;
    const int nw = rows * 64;
    for (int w = tid; w < nw; w += 256) {
        const int r = w >> 6, cc = w & 63;
        ((unsigned int*)lbp[r])[cc] =
            ((const unsigned int*)(bpb + (size_t)(r0 + r) * CRF_K))[cc];
    }
    __syncthreads();

    int tag = tid;
    for (int j = rows - 1; j >= 0; --j) tag = lbp[j][tag];
    maps[((size_t)b * NSEG + s) * CRF_K + tid] = (unsigned char)tag;
}

__global__ __launch_bounds__(256) void crf_compose(
    const float* __restrict__ M, const float* __restrict__ em,
    const unsigned char* __restrict__ maps,
    int* __restrict__ exits, float* __restrict__ out)
{
    const int b   = blockIdx.x;
    const int tid = threadIdx.x;

    __shared__ float s_wv[4];
    __shared__ int   s_wi[4];

    float v = M[((size_t)(CRF_T - 1) * CRF_B + b) * CRF_K + tid]
            + em[((size_t)b * CRF_T + (CRF_T - 1)) * CRF_K + tid];
    int   i = tid;
#pragma unroll
    for (int off = 32; off >= 1; off >>= 1) {
        float ov = __shfl_xor(v, off, 64);
        int   oi = __shfl_xor(i, off, 64);
        if (ov > v || (ov == v && oi < i)) { v = ov; i = oi; }
    }
    const int lane = tid & 63, wv = tid >> 6;
    if (lane == 0) { s_wv[wv] = v; s_wi[wv] = i; }
    __syncthreads();
    if (tid == 0) {
        float bv = s_wv[0]; int bi = s_wi[0];
#pragma unroll
        for (int w = 1; w < 4; ++w)
            if (s_wv[w] > bv) { bv = s_wv[w]; bi = s_wi[w]; }
        out[(size_t)b * CRF_T + (CRF_T - 1)] = (float)bi;
        int E = bi;
        exits[b * NSEG + NSEG - 1] = E;
        const unsigned char* mb = maps + (size_t)b * NSEG * CRF_K;
        for (int s = NSEG - 1; s >= 1; --s) {
            E = mb[(size_t)s * CRF_K + E];
            exits[b * NSEG + s - 1] = E;
        }
    }
}

__global__ __launch_bounds__(256) void crf_emit(
    const unsigned char* __restrict__ bp, const int* __restrict__ exits,
    float* __restrict__ out)
{
    const int b   = blockIdx.x >> 4;
    const int s   = blockIdx.x & 15;
    const int tid = threadIdx.x;
    const int rows = (s == NSEG - 1) ? SEGLEN - 1 : SEGLEN;
    const int r0   = s * SEGLEN;

    __shared__ unsigned char lbp[SEGLEN][CRF_K];

    const unsigned char* bpb = bp + (size_t)b * (CRF_T - 1) * CRF_K;
    const int nw = rows * 64;
    for (int w = tid; w < nw; w += 256) {
        const int r = w >> 6, cc = w & 63;
        ((unsigned int*)lbp[r])[cc] =
            ((const unsigned int*)(bpb + (size_t)(r0 + r) * CRF_K))[cc];
    }
    __syncthreads();

    int tag = tid;
    const bool win = (tid == exits[b * NSEG + s]);
    for (int j = rows - 1; j >= 0; --j) {
        tag = lbp[j][tag];
        if (win) out[(size_t)b * CRF_T + r0 + j] = (float)tag;
    }
}

__global__ void crf_zero_out(float* __restrict__ out, int n)
{
    int i = blockIdx.x * blockDim.x + threadIdx.x;
    if (i < n) out[i] = 0.0f;
}

// ---------------------------------------------------------------------------

extern "C" void kernel_launch(void* const* d_in, const int* in_sizes, int n_in,
                              void* d_out, int out_size, void* d_ws, size_t ws_size,
                              hipStream_t stream) {
    (void)in_sizes; (void)n_in;
    const float* em    = (const float*)d_in[0];   // [B,T,K]
    const float* trans = (const float*)d_in[1];   // [K,K]
    float* out = (float*)d_out;                   // [B,T]

    const size_t M_bytes     = (size_t)CRF_T * CRF_B * CRF_K * sizeof(float); // 64 MB
    const size_t gid_bytes   = (size_t)CRF_T * CRF_B * 128;                   // 8.4 MB
    const size_t bp_bytes    = (size_t)CRF_B * (CRF_T - 1) * CRF_K;           // 16.75 MB
    const size_t maps_bytes  = (size_t)CRF_B * NSEG * CRF_K;                  // 256 KB
    const size_t exits_bytes = (size_t)CRF_B * NSEG * sizeof(int);            // 4 KB

    char* w = (char*)d_ws;
    if (ws_size >= M_bytes + gid_bytes + bp_bytes + maps_bytes + exits_bytes) {
        float*         M     = (float*)w;            w += M_bytes;
        unsigned char* gidp  = (unsigned char*)w;    w += gid_bytes;
        unsigned char* bp    = (unsigned char*)w;    w += bp_bytes;
        unsigned char* maps  = (unsigned char*)w;    w += maps_bytes;
        int*           exits = (int*)w;

        crf_forward_states<<<CRF_B, 1024, 0, stream>>>(em, trans, M, gidp);
        crf_bp_gid<<<CRF_B * 8, 128, 0, stream>>>(M, em, trans, gidp, bp);
        crf_seg_maps<<<CRF_B * NSEG, 256, 0, stream>>>(bp, maps);
        crf_compose<<<CRF_B, 256, 0, stream>>>(M, em, maps, exits, out);
        crf_emit<<<CRF_B * NSEG, 256, 0, stream>>>(bp, exits, out);
    } else if (ws_size >= M_bytes + bp_bytes + maps_bytes + exits_bytes) {
        float*         M     = (float*)w;            w += M_bytes;
        unsigned char* bp    = (unsigned char*)w;    w += bp_bytes;
        unsigned char* maps  = (unsigned char*)w;    w += maps_bytes;
        int*           exits = (int*)w;

        crf_forward_states<<<CRF_B, 1024, 0, stream>>>(em, trans, M, nullptr);
        crf_bp_matrix<<<CRF_B * NSEG, 1024, 0, stream>>>(M, em, trans, bp);
        crf_seg_maps<<<CRF_B * NSEG, 256, 0, stream>>>(bp, maps);
        crf_compose<<<CRF_B, 256, 0, stream>>>(M, em, maps, exits, out);
        crf_emit<<<CRF_B * NSEG, 256, 0, stream>>>(bp, exits, out);
    } else {
        crf_zero_out<<<(out_size + 255) / 256, 256, 0, stream>>>(out, out_size);
    }
}

// Round 11
// 1105.316 us; speedup vs baseline: 1.6766x; 1.1918x over previous
//
#include <hip/hip_runtime.h>

// CRF Viterbi decode: B=64, T=1024, K=256.
// emissions [B,T,K] f32, transitions [K,K] f32 (prev->next). out [B,T] f32 tags.
//
// Path A (M 64MB + gidp 8.4MB + bp 16.75MB + maps 256KB + exits 4KB ~ 89.4MB):
//   1. crf_forward_states : proven body; reducer = cheap max3 tree; gid
//      (first 32-prev group attaining the max) computed DEFERRED one step
//      later, overlapped with the next step's chunk compute (r10 post-mortem:
//      in-reducer gid cost +113us on the serial section).
//   2. crf_bp_gid         : 4 waves/block + gid prefetch pipeline (r10: 1
//      wave/SIMD serial chain = 357us latency-bound).
//   3. crf_seg_maps / crf_compose / crf_emit : proven segmented chase.
// Path B: forward(no gid) + bp_matrix full scan + chase.  Path C: zero.

#define CRF_B 64
#define CRF_T 1024
#define CRF_K 256
#define NSEG  16
#define SEGLEN 64

#define FG 8
#define FP 32

// ---------------------------------------------------------------------------
// Forward
// ---------------------------------------------------------------------------

#define LD4(v, p, col) { \
    v.x = trans[(size_t)(p) * CRF_K + (col)]; \
    v.y = trans[(size_t)((p) + 1) * CRF_K + (col)]; \
    v.z = trans[(size_t)((p) + 2) * CRF_K + (col)]; \
    v.w = trans[(size_t)((p) + 3) * CRF_K + (col)]; }

// max3-shaped: fmaxf(fmaxf(x,y),z) fuses to v_max3_f32
#define FWD_CHUNK(idx, ta, tb) { \
    float4 sv = sp[idx]; \
    float a0 = sv.x + ta.x; \
    float a1 = sv.y + ta.y; \
    float a2 = sv.z + ta.z; \
    float a3 = sv.w + ta.w; \
    float r0 = fmaxf(fmaxf(a0, a1), a2); \
    m0 = fmaxf(fmaxf(r0, a3), m0); \
    float c0 = sv.x + tb.x; \
    float c1 = sv.y + tb.y; \
    float c2 = sv.z + tb.z; \
    float c3 = sv.w + tb.w; \
    float r1 = fmaxf(fmaxf(c0, c1), c2); \
    m1 = fmaxf(fmaxf(r1, c3), m1); }

__global__ __launch_bounds__(1024, 4) void crf_forward_states(
    const float* __restrict__ em, const float* __restrict__ trans,
    float* __restrict__ M, unsigned char* __restrict__ gidp)
{
    const int b   = blockIdx.x;
    const int tid = threadIdx.x;
    const int g   = tid >> 7;      // prev group 0..7
    const int c   = tid & 127;     // columns c and c+128

    __shared__ __align__(16) float s_state[CRF_K];
    __shared__ float s_partial[FG][CRF_K];

    const int pbase = g * FP;
    const int c2    = c + 128;

    float4 ta0, ta1, ta2, ta3, ta4, ta5, ta6, ta7;
    float4 tb0, tb1, tb2, tb3, tb4, tb5, tb6, tb7;
    LD4(ta0, pbase +  0, c)  LD4(ta1, pbase +  4, c)
    LD4(ta2, pbase +  8, c)  LD4(ta3, pbase + 12, c)
    LD4(ta4, pbase + 16, c)  LD4(ta5, pbase + 20, c)
    LD4(ta6, pbase + 24, c)  LD4(ta7, pbase + 28, c)
    LD4(tb0, pbase +  0, c2) LD4(tb1, pbase +  4, c2)
    LD4(tb2, pbase +  8, c2) LD4(tb3, pbase + 12, c2)
    LD4(tb4, pbase + 16, c2) LD4(tb5, pbase + 20, c2)
    LD4(tb6, pbase + 24, c2) LD4(tb7, pbase + 28, c2)

    const float* emb = em + (size_t)b * CRF_T * CRF_K;
    if (tid < CRF_K) s_state[tid] = emb[tid];          // state[0] = em[0]
    float e_cur = 0.0f;
    if (tid < CRF_K) e_cur = emb[CRF_K + tid];         // emission for t = 1
    __syncthreads();

    // deferred-gid state (saved across the barrier; stored one step later)
    float sp0 = 0, sp1 = 0, sp2 = 0, sp3 = 0;
    float sp4 = 0, sp5 = 0, sp6 = 0, sp7 = 0;
    float sbv = 0;

    for (int t = 1; t < CRF_T; ++t) {
        // deferred gid store for step t-1 (reads saved regs only; overlaps
        // all waves' chunk compute instead of the serial reducer section)
        if (gidp && tid < CRF_K && t > 1) {
            int bg = 7;
            if (sp6 == sbv) bg = 6;
            if (sp5 == sbv) bg = 5;
            if (sp4 == sbv) bg = 4;
            if (sp3 == sbv) bg = 3;
            if (sp2 == sbv) bg = 2;
            if (sp1 == sbv) bg = 1;
            if (sp0 == sbv) bg = 0;
            int g1 = __shfl_down(bg, 1, 64);
            if ((tid & 1) == 0)
                gidp[((size_t)(t - 1) * CRF_B + b) * 128 + (tid >> 1)] =
                    (unsigned char)(bg | (g1 << 4));
        }

        float e_next = 0.0f;
        if (tid < CRF_K && t + 1 < CRF_T)
            e_next = emb[(t + 1) * CRF_K + tid];

        float m0 = -INFINITY, m1 = -INFINITY;
        const float4* sp = (const float4*)(s_state + pbase);
        FWD_CHUNK(0, ta0, tb0) FWD_CHUNK(1, ta1, tb1)
        FWD_CHUNK(2, ta2, tb2) FWD_CHUNK(3, ta3, tb3)
        FWD_CHUNK(4, ta4, tb4) FWD_CHUNK(5, ta5, tb5)
        FWD_CHUNK(6, ta6, tb6) FWD_CHUNK(7, ta7, tb7)

        s_partial[g][c]  = m0;
        s_partial[g][c2] = m1;
        __syncthreads();
        if (tid < CRF_K) {
            float p0 = s_partial[0][tid], p1 = s_partial[1][tid];
            float p2 = s_partial[2][tid], p3 = s_partial[3][tid];
            float p4 = s_partial[4][tid], p5 = s_partial[5][tid];
            float p6 = s_partial[6][tid], p7 = s_partial[7][tid];
            float q0 = fmaxf(fmaxf(p0, p1), p2);    // max3
            float q1 = fmaxf(fmaxf(p3, p4), p5);    // max3
            float bv = fmaxf(fmaxf(fmaxf(q0, q1), p6), p7);
            s_state[tid] = bv + e_cur;
            M[((size_t)t * CRF_B + b) * CRF_K + tid] = bv;   // PRE-emission
            sp0 = p0; sp1 = p1; sp2 = p2; sp3 = p3;
            sp4 = p4; sp5 = p5; sp6 = p6; sp7 = p7; sbv = bv;
        }
        __syncthreads();
        e_cur = e_next;
    }

    // flush gid for the final row (t = CRF_T-1)
    if (gidp && tid < CRF_K) {
        int bg = 7;
        if (sp6 == sbv) bg = 6;
        if (sp5 == sbv) bg = 5;
        if (sp4 == sbv) bg = 4;
        if (sp3 == sbv) bg = 3;
        if (sp2 == sbv) bg = 2;
        if (sp1 == sbv) bg = 1;
        if (sp0 == sbv) bg = 0;
        int g1 = __shfl_down(bg, 1, 64);
        if ((tid & 1) == 0)
            gidp[((size_t)(CRF_T - 1) * CRF_B + b) * 128 + (tid >> 1)] =
                (unsigned char)(bg | (g1 << 4));
    }
}

// ---------------------------------------------------------------------------
// bp via gid: 512 blocks (b x cg4 x ts2) x 256 thr (4 waves, t1 stride 4).
// 64KB transposed trans tile; gid byte for next iteration prefetched.
// ---------------------------------------------------------------------------

#define BPG_CHUNK(j) { \
    float4 mm = M4[j]; float4 ee = E4[j]; \
    float s0 = mm.x + ee.x, s1 = mm.y + ee.y; \
    float s2 = mm.z + ee.z, s3 = mm.w + ee.w; \
    float t0v = s_tile[base + 4*(j) + 0][lane]; \
    float t1v = s_tile[base + 4*(j) + 1][lane]; \
    float t2v = s_tile[base + 4*(j) + 2][lane]; \
    float t3v = s_tile[base + 4*(j) + 3][lane]; \
    float v0 = s0 + t0v; if (v0 > best) { best = v0; arg = base + 4*(j); } \
    float v1 = s1 + t1v; if (v1 > best) { best = v1; arg = base + 4*(j) + 1; } \
    float v2 = s2 + t2v; if (v2 > best) { best = v2; arg = base + 4*(j) + 2; } \
    float v3 = s3 + t3v; if (v3 > best) { best = v3; arg = base + 4*(j) + 3; } }

#define BPG_CHUNK0(j) { \
    float4 ee = E4[j]; \
    float t0v = s_tile[base + 4*(j) + 0][lane]; \
    float t1v = s_tile[base + 4*(j) + 1][lane]; \
    float t2v = s_tile[base + 4*(j) + 2][lane]; \
    float t3v = s_tile[base + 4*(j) + 3][lane]; \
    float v0 = ee.x + t0v; if (v0 > best) { best = v0; arg = base + 4*(j); } \
    float v1 = ee.y + t1v; if (v1 > best) { best = v1; arg = base + 4*(j) + 1; } \
    float v2 = ee.z + t2v; if (v2 > best) { best = v2; arg = base + 4*(j) + 2; } \
    float v3 = ee.w + t3v; if (v3 > best) { best = v3; arg = base + 4*(j) + 3; } }

__global__ __launch_bounds__(256) void crf_bp_gid(
    const float* __restrict__ M, const float* __restrict__ em,
    const float* __restrict__ trans, const unsigned char* __restrict__ gidp,
    unsigned char* __restrict__ bp)
{
    const int b    = blockIdx.x >> 3;
    const int cg   = (blockIdx.x >> 1) & 3;
    const int ts   = blockIdx.x & 1;
    const int tid  = threadIdx.x;
    const int lane = tid & 63;
    const int w    = tid >> 6;      // wave 0..3

    __shared__ float s_tile[CRF_K][64];   // 64 KB: s_tile[prev][col]

    const int k0 = cg * 64;
    for (int idx = tid; idx < CRF_K * 64; idx += 256) {
        const int p = idx >> 6, cc = idx & 63;
        s_tile[p][cc] = trans[(size_t)p * CRF_K + k0 + cc];
    }
    __syncthreads();

    const int t_lo = ts * 512;
    const int t_hi = ts ? (CRF_T - 1) : 512;
    const int half = (k0 >> 1) + (lane >> 1);
    const int odd  = lane & 1;

    int t1 = t_lo + w;
    if (t1 >= t_hi) return;
    unsigned char gb = gidp[((size_t)(t1 + 1) * CRF_B + b) * 128 + half];

    for (; t1 < t_hi; t1 += 4) {
        const int tn = t1 + 4;
        unsigned char gb_next = 0;
        if (tn < t_hi)                         // prefetch next gid byte
            gb_next = gidp[((size_t)(tn + 1) * CRF_B + b) * 128 + half];

        const int g    = odd ? ((gb >> 4) & 7) : (gb & 7);
        const int base = g << 5;
        const float4* E4 =
            (const float4*)(em + ((size_t)b * CRF_T + t1) * CRF_K + base);
        float best = -INFINITY; int arg = base;
        if (t1 == 0) {                         // state[0] = em[0]
            BPG_CHUNK0(0) BPG_CHUNK0(1) BPG_CHUNK0(2) BPG_CHUNK0(3)
            BPG_CHUNK0(4) BPG_CHUNK0(5) BPG_CHUNK0(6) BPG_CHUNK0(7)
        } else {
            const float4* M4 =
                (const float4*)(M + ((size_t)t1 * CRF_B + b) * CRF_K + base);
            BPG_CHUNK(0) BPG_CHUNK(1) BPG_CHUNK(2) BPG_CHUNK(3)
            BPG_CHUNK(4) BPG_CHUNK(5) BPG_CHUNK(6) BPG_CHUNK(7)
        }
        bp[((size_t)b * (CRF_T - 1) + t1) * CRF_K + k0 + lane] =
            (unsigned char)arg;
        gb = gb_next;
    }
}

// ---------------------------------------------------------------------------
// Fallback-B backpointers: full-scan bp_matrix (proven), state = M+em.
// ---------------------------------------------------------------------------

__global__ __launch_bounds__(1024, 2) void crf_bp_matrix(
    const float* __restrict__ M, const float* __restrict__ em,
    const float* __restrict__ trans, unsigned char* __restrict__ bp)
{
    const int b   = blockIdx.x >> 4;
    const int seg = blockIdx.x & 15;
    const int tid = threadIdx.x;
    const int g   = tid >> 8;      // 0..3
    const int k   = tid & 255;

    __shared__ __align__(16) float s_row[CRF_K];
    __shared__ float s_pv[4][CRF_K];
    __shared__ int   s_pi[4][CRF_K];

    const int pbase = g * 64;
    float4 tr[16];
#pragma unroll
    for (int i = 0; i < 16; ++i) {
        const int p = pbase + 4 * i;
        tr[i].x = trans[(p + 0) * CRF_K + k];
        tr[i].y = trans[(p + 1) * CRF_K + k];
        tr[i].z = trans[(p + 2) * CRF_K + k];
        tr[i].w = trans[(p + 3) * CRF_K + k];
    }

    const int t_lo = seg * SEGLEN;
    const int t_hi = min(t_lo + SEGLEN, CRF_T - 1);
    unsigned char* bpb = bp + (size_t)b * (CRF_T - 1) * CRF_K;

    for (int t1 = t_lo; t1 < t_hi; ++t1) {
        if (tid < CRF_K) {
            float ev = em[((size_t)b * CRF_T + t1) * CRF_K + tid];
            float sv = ev;
            if (t1 > 0) sv = M[((size_t)t1 * CRF_B + b) * CRF_K + tid] + ev;
            s_row[tid] = sv;
        }
        __syncthreads();

        float best = -INFINITY;
        int   arg  = pbase;
        const float4* spp = (const float4*)(s_row + pbase);
#pragma unroll
        for (int i = 0; i < 16; ++i) {
            float4 st = spp[i];
            const int p = pbase + 4 * i;
            float s0 = st.x + tr[i].x;
            float s1 = st.y + tr[i].y;
            float s2 = st.z + tr[i].z;
            float s3 = st.w + tr[i].w;
            if (s0 > best) { best = s0; arg = p; }
            if (s1 > best) { best = s1; arg = p + 1; }
            if (s2 > best) { best = s2; arg = p + 2; }
            if (s3 > best) { best = s3; arg = p + 3; }
        }
        s_pv[g][k] = best;
        s_pi[g][k] = arg;
        __syncthreads();
        if (tid < CRF_K) {
            float bv = s_pv[0][tid];
            int   ba = s_pi[0][tid];
#pragma unroll
            for (int j = 1; j < 4; ++j) {
                float v = s_pv[j][tid];
                if (v > bv) { bv = v; ba = s_pi[j][tid]; }
            }
            bpb[(size_t)t1 * CRF_K + tid] = (unsigned char)ba;
        }
        __syncthreads();
    }
}

// ---------------------------------------------------------------------------
// Segmented chase (proven): seg_maps -> compose -> emit.
// ---------------------------------------------------------------------------

__global__ __launch_bounds__(256) void crf_seg_maps(
    const unsigned char* __restrict__ bp, unsigned char* __restrict__ maps)
{
    const int b   = blockIdx.x >> 4;
    const int s   = blockIdx.x & 15;
    const int tid = threadIdx.x;
    const int rows = (s == NSEG - 1) ? SEGLEN - 1 : SEGLEN;
    const int r0   = s * SEGLEN;

    __shared__ unsigned char lbp[SEGLEN][CRF_K];   // 16 KB

    const unsigned char* bpb = bp + (size_t)b * (CRF_T - 1) * CRF_K;
    const int nw = rows * 64;
    for (int w = tid; w < nw; w += 256) {
        const int r = w >> 6, cc = w & 63;
        ((unsigned int*)lbp[r])[cc] =
            ((const unsigned int*)(bpb + (size_t)(r0 + r) * CRF_K))[cc];
    }
    __syncthreads();

    int tag = tid;
    for (int j = rows - 1; j >= 0; --j) tag = lbp[j][tag];
    maps[((size_t)b * NSEG + s) * CRF_K + tid] = (unsigned char)tag;
}

__global__ __launch_bounds__(256) void crf_compose(
    const float* __restrict__ M, const float* __restrict__ em,
    const unsigned char* __restrict__ maps,
    int* __restrict__ exits, float* __restrict__ out)
{
    const int b   = blockIdx.x;
    const int tid = threadIdx.x;

    __shared__ float s_wv[4];
    __shared__ int   s_wi[4];

    float v = M[((size_t)(CRF_T - 1) * CRF_B + b) * CRF_K + tid]
            + em[((size_t)b * CRF_T + (CRF_T - 1)) * CRF_K + tid];
    int   i = tid;
#pragma unroll
    for (int off = 32; off >= 1; off >>= 1) {
        float ov = __shfl_xor(v, off, 64);
        int   oi = __shfl_xor(i, off, 64);
        if (ov > v || (ov == v && oi < i)) { v = ov; i = oi; }
    }
    const int lane = tid & 63, wv = tid >> 6;
    if (lane == 0) { s_wv[wv] = v; s_wi[wv] = i; }
    __syncthreads();
    if (tid == 0) {
        float bv = s_wv[0]; int bi = s_wi[0];
#pragma unroll
        for (int w = 1; w < 4; ++w)
            if (s_wv[w] > bv) { bv = s_wv[w]; bi = s_wi[w]; }
        out[(size_t)b * CRF_T + (CRF_T - 1)] = (float)bi;
        int E = bi;
        exits[b * NSEG + NSEG - 1] = E;
        const unsigned char* mb = maps + (size_t)b * NSEG * CRF_K;
        for (int s = NSEG - 1; s >= 1; --s) {
            E = mb[(size_t)s * CRF_K + E];
            exits[b * NSEG + s - 1] = E;
        }
    }
}

__global__ __launch_bounds__(256) void crf_emit(
    const unsigned char* __restrict__ bp, const int* __restrict__ exits,
    float* __restrict__ out)
{
    const int b   = blockIdx.x >> 4;
    const int s   = blockIdx.x & 15;
    const int tid = threadIdx.x;
    const int rows = (s == NSEG - 1) ? SEGLEN - 1 : SEGLEN;
    const int r0   = s * SEGLEN;

    __shared__ unsigned char lbp[SEGLEN][CRF_K];

    const unsigned char* bpb = bp + (size_t)b * (CRF_T - 1) * CRF_K;
    const int nw = rows * 64;
    for (int w = tid; w < nw; w += 256) {
        const int r = w >> 6, cc = w & 63;
        ((unsigned int*)lbp[r])[cc] =
            ((const unsigned int*)(bpb + (size_t)(r0 + r) * CRF_K))[cc];
    }
    __syncthreads();

    int tag = tid;
    const bool win = (tid == exits[b * NSEG + s]);
    for (int j = rows - 1; j >= 0; --j) {
        tag = lbp[j][tag];
        if (win) out[(size_t)b * CRF_T + r0 + j] = (float)tag;
    }
}

__global__ void crf_zero_out(float* __restrict__ out, int n)
{
    int i = blockIdx.x * blockDim.x + threadIdx.x;
    if (i < n) out[i] = 0.0f;
}

// ---------------------------------------------------------------------------

extern "C" void kernel_launch(void* const* d_in, const int* in_sizes, int n_in,
                              void* d_out, int out_size, void* d_ws, size_t ws_size,
                              hipStream_t stream) {
    (void)in_sizes; (void)n_in;
    const float* em    = (const float*)d_in[0];   // [B,T,K]
    const float* trans = (const float*)d_in[1];   // [K,K]
    float* out = (float*)d_out;                   // [B,T]

    const size_t M_bytes     = (size_t)CRF_T * CRF_B * CRF_K * sizeof(float); // 64 MB
    const size_t gid_bytes   = (size_t)CRF_T * CRF_B * 128;                   // 8.4 MB
    const size_t bp_bytes    = (size_t)CRF_B * (CRF_T - 1) * CRF_K;           // 16.75 MB
    const size_t maps_bytes  = (size_t)CRF_B * NSEG * CRF_K;                  // 256 KB
    const size_t exits_bytes = (size_t)CRF_B * NSEG * sizeof(int);            // 4 KB

    char* w = (char*)d_ws;
    if (ws_size >= M_bytes + gid_bytes + bp_bytes + maps_bytes + exits_bytes) {
        float*         M     = (float*)w;            w += M_bytes;
        unsigned char* gidp  = (unsigned char*)w;    w += gid_bytes;
        unsigned char* bp    = (unsigned char*)w;    w += bp_bytes;
        unsigned char* maps  = (unsigned char*)w;    w += maps_bytes;
        int*           exits = (int*)w;

        crf_forward_states<<<CRF_B, 1024, 0, stream>>>(em, trans, M, gidp);
        crf_bp_gid<<<CRF_B * 8, 256, 0, stream>>>(M, em, trans, gidp, bp);
        crf_seg_maps<<<CRF_B * NSEG, 256, 0, stream>>>(bp, maps);
        crf_compose<<<CRF_B, 256, 0, stream>>>(M, em, maps, exits, out);
        crf_emit<<<CRF_B * NSEG, 256, 0, stream>>>(bp, exits, out);
    } else if (ws_size >= M_bytes + bp_bytes + maps_bytes + exits_bytes) {
        float*         M     = (float*)w;            w += M_bytes;
        unsigned char* bp    = (unsigned char*)w;    w += bp_bytes;
        unsigned char* maps  = (unsigned char*)w;    w += maps_bytes;
        int*           exits = (int*)w;

        crf_forward_states<<<CRF_B, 1024, 0, stream>>>(em, trans, M, nullptr);
        crf_bp_matrix<<<CRF_B * NSEG, 1024, 0, stream>>>(M, em, trans, bp);
        crf_seg_maps<<<CRF_B * NSEG, 256, 0, stream>>>(bp, maps);
        crf_compose<<<CRF_B, 256, 0, stream>>>(M, em, maps, exits, out);
        crf_emit<<<CRF_B * NSEG, 256, 0, stream>>>(bp, exits, out);
    } else {
        crf_zero_out<<<(out_size + 255) / 256, 256, 0, stream>>>(out, out_size);
    }
}